// Round 7
// baseline (7841.638 us; speedup 1.0000x reference)
//
#include <hip/hip_runtime.h>
#include <stdint.h>

// LSTM N=32, T=2048, D=H=512. Persistent kernel, 8 groups x 32 WGs (grid=256=#CUs,
// co-resident). Each WG owns 16 hidden units (64 gate rows); weights stationary in
// VGPR MFMA A-fragments, rows ordered unit*4+gate. x and h split hi/lo bf16
// (two MFMA chains) for ~f32 accuracy.
//
// R10 = R8 skeleton (best, 5632us; R9's GEMM-ahead reverted - it added pure
// overhead: identical MfmaUtil*dur, +21% VALU cycles) + three serial-path cuts:
// 1) async x-stage (T14): x(t+1) global loads issued at step top with the h-load
//    issue; counted vmcnt(2) waits h only (4 oldest); LDS write after mid-barrier.
//    Removes ~900cy of bare HBM latency from the barrier-bounded region.
// 2) hi/lo PLANE LDS layout: x packs straight to planes at staging; h-strip does
//    8 perms once per step (vs 128 per MFMA phase in buildfrag). Fragment loads
//    are plain ds_read_b128 now. -~500 VALU cy/step.
// 3) publish (h tagged store) + y store moved BELOW the end barrier: their
//    completion overlaps the next step's issue+x-MFMA instead of being drained
//    by the barrier's vmcnt(0). xpk pack prologue deleted (x read f32 inline).
// h exchange: R8's proven tagged fire-and-forget protocol, all sc0 sc1 (MALL).

#define T_STEPS 2048
#define HD 512
#define NBATCH 32
#define PSTRIDE 260   // plane row stride (dwords): 260%32==4 -> 2-way max (free)

typedef __attribute__((ext_vector_type(8))) short short8;
typedef __attribute__((ext_vector_type(4))) float f32x4;
typedef __attribute__((ext_vector_type(4))) uint u32x4;
typedef __attribute__((ext_vector_type(2))) uint u32x2;

static __device__ __forceinline__ uint bf_rne(float f) {
    uint u = __builtin_bit_cast(uint, f);
    return (u + 0x7FFFu + ((u >> 16) & 1u)) >> 16;
}
static __device__ __forceinline__ float bf_f(uint h) {
    return __builtin_bit_cast(float, h << 16);
}
// f32 -> (bf16_hi<<16) | bf16_lo  (publish format)
static __device__ __forceinline__ uint packsplit(float f) {
    uint hi = bf_rne(f);
    uint lo = bf_rne(f - bf_f(hi));
    return (hi << 16) | lo;
}

static __device__ __forceinline__ float sigf(float v) { return 1.f / (1.f + __expf(-v)); }
static __device__ __forceinline__ float tanhfast(float v) { return 2.f / (1.f + __expf(-2.f * v)) - 1.f; }

// ---- MALL-coherent (device-scope) ops: sc0 sc1 bypass L1/L2 ----
static __device__ __forceinline__ void st_mall2(uint* p, u32x2 v) {
    asm volatile("global_store_dwordx2 %0, %1, off sc0 sc1" :: "v"(p), "v"(v) : "memory");
}
// issue four 16B tagged loads (no wait) — results unread until a tied wait
static __device__ __forceinline__ void ld_mall_issue4(const uint* p0, const uint* p1,
                                                      const uint* p2, const uint* p3,
                                                      u32x4& a, u32x4& b, u32x4& c, u32x4& d) {
    asm volatile("global_load_dwordx4 %0, %4, off sc0 sc1\n\t"
                 "global_load_dwordx4 %1, %5, off sc0 sc1\n\t"
                 "global_load_dwordx4 %2, %6, off sc0 sc1\n\t"
                 "global_load_dwordx4 %3, %7, off sc0 sc1"
                 : "=&v"(a), "=&v"(b), "=&v"(c), "=&v"(d)
                 : "v"(p0), "v"(p1), "v"(p2), "v"(p3) : "memory");
}
static __device__ __forceinline__ void wait_tied4(u32x4& a, u32x4& b, u32x4& c, u32x4& d) {
    asm volatile("s_waitcnt vmcnt(0)" : "+v"(a), "+v"(b), "+v"(c), "+v"(d) :: "memory");
}
// wait until only the 2 newest VMEM ops (the x loads) remain outstanding
static __device__ __forceinline__ void wait_vm2_tied(u32x4& a, u32x4& b, u32x4& c, u32x4& d) {
    asm volatile("s_waitcnt vmcnt(2)" : "+v"(a), "+v"(b), "+v"(c), "+v"(d) :: "memory");
}

__global__ __launch_bounds__(256, 1) void lstm_pers(
    const float* __restrict__ x, const float* __restrict__ Wih,
    const float* __restrict__ bih, const float* __restrict__ Whh,
    const float* __restrict__ bhh, float* __restrict__ y,
    uint* __restrict__ hq)
{
    // hi/lo bf16 planes: row = one batch, 256 dwords = 512 bf16 (k-major, 2/word)
    __shared__ uint xsh_hi[4 * PSTRIDE], xsh_lo[4 * PSTRIDE];
    __shared__ uint hs_hi[4 * PSTRIDE], hs_lo[4 * PSTRIDE];

    const int b   = blockIdx.x;
    const int g   = b & 7;
    const int w   = b >> 3;
    const int tid = threadIdx.x;
    const int wv  = tid >> 6;
    const int l   = tid & 63;
    const int q   = l >> 4;
    const int m   = l & 15;

    // ---- stationary weight A-fragments: rows ordered unit*4+gate ----
    const int gateA = m & 3, ulA = m >> 2;
    const int Arow  = gateA * HD + ((w << 4) + (wv << 2) + ulA);
    short8 wf[32];
#pragma unroll
    for (int kt = 0; kt < 32; ++kt) {
        const int k0 = kt * 32 + q * 8;
        const float* src = (k0 < HD) ? (Wih + (size_t)Arow * HD + k0)
                                     : (Whh + (size_t)Arow * HD + (k0 - HD));
        float4 a  = ((const float4*)src)[0];
        float4 c4 = ((const float4*)src)[1];
        uint4 uu;
        uu.x = bf_rne(a.x)  | (bf_rne(a.y)  << 16);
        uu.y = bf_rne(a.z)  | (bf_rne(a.w)  << 16);
        uu.z = bf_rne(c4.x) | (bf_rne(c4.y) << 16);
        uu.w = bf_rne(c4.z) | (bf_rne(c4.w) << 16);
        wf[kt] = __builtin_bit_cast(short8, uu);
    }

    const int unitC = (w << 4) + (wv << 2) + q;
    float bias_[4];
#pragma unroll
    for (int i = 0; i < 4; ++i) bias_[i] = bih[i * HD + unitC] + bhh[i * HD + unitC];

    const bool act = (m < 4);
    const int  fro = (l & 3) * PSTRIDE;     // fragment-read row base
    int budget = 1 << 21;                   // spin budget: guarantees termination

    // pack one float4 (4 consecutive k) into hi/lo plane words at widx (2 words)
    auto pack_x = [&](const float4& f, int widx) {
        uint h0 = bf_rne(f.x), h1 = bf_rne(f.y), h2 = bf_rne(f.z), h3 = bf_rne(f.w);
        uint l0 = bf_rne(f.x - bf_f(h0)), l1 = bf_rne(f.y - bf_f(h1));
        uint l2 = bf_rne(f.z - bf_f(h2)), l3 = bf_rne(f.w - bf_f(h3));
        u32x2 hw; hw.x = h0 | (h1 << 16); hw.y = h2 | (h3 << 16);
        u32x2 lw; lw.x = l0 | (l1 << 16); lw.y = l2 | (l3 << 16);
        *(u32x2*)&xsh_hi[wv * PSTRIDE + widx] = hw;
        *(u32x2*)&xsh_lo[wv * PSTRIDE + widx] = lw;
    };

    // ---- prologue: stage x(0) into planes ----
    {
        const float* xp = x + (size_t)(g * 4 + wv) * T_STEPS * HD;
        float4 A = *(const float4*)(xp + 4 * l);
        float4 C = *(const float4*)(xp + 256 + 4 * l);
        pack_x(A, 2 * l);
        pack_x(C, 128 + 2 * l);
    }
    __syncthreads();

    const f32x4 zero4 = {0.f, 0.f, 0.f, 0.f};
    float cst = 0.f;

    for (int t = 0; t < T_STEPS; ++t) {
        f32x4 a0 = zero4, a1 = zero4, b0 = zero4, b1 = zero4;
        u32x4 va, vb, vc, vd;
        float4 XA, XC;
        const bool havex = (t + 1 < T_STEPS);

        // --- issue phase: h loads (4, oldest) then x(t+1) loads (2, newest) ---
        uint* const hp = hq + (size_t)(((t - 1) & 1) * NBATCH + g * 4 + wv) * (HD * 2);
        if (t > 0)
            ld_mall_issue4(hp + 4 * l, hp + 256 + 4 * l, hp + 512 + 4 * l,
                           hp + 768 + 4 * l, va, vb, vc, vd);
        if (havex) {
            const float* xp = x + ((size_t)(g * 4 + wv) * T_STEPS + t + 1) * HD;
            XA = *(const float4*)(xp + 4 * l);
            XC = *(const float4*)(xp + 256 + 4 * l);
        }

        // --- x-projection MFMA from planes (staged last step) ---
#pragma unroll
        for (int kt = 0; kt < 16; ++kt) {
            short8 bh = *(const short8*)&xsh_hi[fro + kt * 16 + q * 4];
            short8 bl = *(const short8*)&xsh_lo[fro + kt * 16 + q * 4];
            if (kt & 1) {
                a1 = __builtin_amdgcn_mfma_f32_16x16x32_bf16(wf[kt], bh, a1, 0, 0, 0);
                b1 = __builtin_amdgcn_mfma_f32_16x16x32_bf16(wf[kt], bl, b1, 0, 0, 0);
            } else {
                a0 = __builtin_amdgcn_mfma_f32_16x16x32_bf16(wf[kt], bh, a0, 0, 0, 0);
                b0 = __builtin_amdgcn_mfma_f32_16x16x32_bf16(wf[kt], bl, b0, 0, 0, 0);
            }
        }

        if (t > 0) {
            // --- tag poll: counted wait (h only), retry path drains all ---
            if (havex) wait_vm2_tied(va, vb, vc, vd);
            else       wait_tied4(va, vb, vc, vd);
            const uint want = (uint)t;
            for (;;) {
                int ok = (va.y == want) & (va.w == want) & (vb.y == want) & (vb.w == want)
                       & (vc.y == want) & (vc.w == want) & (vd.y == want) & (vd.w == want);
                if (__all(ok)) break;
                if (--budget <= 0) break;
                ld_mall_issue4(hp + 4 * l, hp + 256 + 4 * l, hp + 512 + 4 * l,
                               hp + 768 + 4 * l, va, vb, vc, vd);
                wait_tied4(va, vb, vc, vd);
            }
            // --- strip to planes: 2 perms per 16B, 8 ds_write_b32 total ---
            hs_hi[wv * PSTRIDE + l]       = __builtin_amdgcn_perm(va.z, va.x, 0x07060302u);
            hs_lo[wv * PSTRIDE + l]       = __builtin_amdgcn_perm(va.z, va.x, 0x05040100u);
            hs_hi[wv * PSTRIDE + 64 + l]  = __builtin_amdgcn_perm(vb.z, vb.x, 0x07060302u);
            hs_lo[wv * PSTRIDE + 64 + l]  = __builtin_amdgcn_perm(vb.z, vb.x, 0x05040100u);
            hs_hi[wv * PSTRIDE + 128 + l] = __builtin_amdgcn_perm(vc.z, vc.x, 0x07060302u);
            hs_lo[wv * PSTRIDE + 128 + l] = __builtin_amdgcn_perm(vc.z, vc.x, 0x05040100u);
            hs_hi[wv * PSTRIDE + 192 + l] = __builtin_amdgcn_perm(vd.z, vd.x, 0x07060302u);
            hs_lo[wv * PSTRIDE + 192 + l] = __builtin_amdgcn_perm(vd.z, vd.x, 0x05040100u);
        }
        __syncthreads();   // hs ready for all waves; xsh(t) reads done (stage below)

        // --- stage x(t+1) into planes (regs arrived long ago; overlapped) ---
        if (havex) {
            pack_x(XA, 2 * l);
            pack_x(XC, 128 + 2 * l);
        }

        // --- h-recurrence MFMA ---
        if (t > 0) {
#pragma unroll
            for (int kt = 0; kt < 16; ++kt) {
                short8 bh = *(const short8*)&hs_hi[fro + kt * 16 + q * 4];
                short8 bl = *(const short8*)&hs_lo[fro + kt * 16 + q * 4];
                if (kt & 1) {
                    a1 = __builtin_amdgcn_mfma_f32_16x16x32_bf16(wf[16 + kt], bh, a1, 0, 0, 0);
                    b1 = __builtin_amdgcn_mfma_f32_16x16x32_bf16(wf[16 + kt], bl, b1, 0, 0, 0);
                } else {
                    a0 = __builtin_amdgcn_mfma_f32_16x16x32_bf16(wf[16 + kt], bh, a0, 0, 0, 0);
                    b0 = __builtin_amdgcn_mfma_f32_16x16x32_bf16(wf[16 + kt], bl, b0, 0, 0, 0);
                }
            }
        }

        // --- activation (act lanes own one unit each) ---
        const float v0 = a0.x + a1.x + b0.x + b1.x + bias_[0];   // i
        const float v1 = a0.y + a1.y + b0.y + b1.y + bias_[1];   // f
        const float v2 = a0.z + a1.z + b0.z + b1.z + bias_[2];   // o
        const float v3 = a0.w + a1.w + b0.w + b1.w + bias_[3];   // g
        const float ig = sigf(v0), fg = sigf(v1), og = sigf(v2), gg = tanhfast(v3);
        cst = fg * cst + ig * gg;
        const float hv = og * tanhfast(cst);
        const uint  p  = packsplit(hv);

        __syncthreads();   // hs reads done before next strip; xsh staged before reads

        if (act) {
            // publish AFTER the barrier: store completion overlaps the next step's
            // issue+x-MFMA window instead of being drained by the barrier itself
            const int bi = g * 4 + m;
            uint* dst = hq + (size_t)((t & 1) * NBATCH + bi) * (HD * 2) + unitC * 2;
            st_mall2(dst, (u32x2){p, (uint)t + 1u});
            y[((size_t)bi * T_STEPS + t) * HD + unitC] =
                __builtin_bit_cast(float, p & 0xFFFF0000u)
              + __builtin_bit_cast(float, p << 16);
        }
    }
}

extern "C" void kernel_launch(void* const* d_in, const int* in_sizes, int n_in,
                              void* d_out, int out_size, void* d_ws, size_t ws_size,
                              hipStream_t stream) {
    (void)in_sizes; (void)n_in; (void)out_size; (void)ws_size;
    const float* x   = (const float*)d_in[0];
    const float* Wih = (const float*)d_in[1];
    const float* bih = (const float*)d_in[2];
    const float* Whh = (const float*)d_in[3];
    const float* bhh = (const float*)d_in[4];
    float* y = (float*)d_out;

    // workspace: tagged hbuf only (2 slots x 32 x 512 x 8B = 256K)
    uint* hq = (uint*)d_ws;
    // zero tags every launch (stale tags must never read as fresh)
    hipMemsetAsync(hq, 0, 262144, stream);
    lstm_pers<<<dim3(256), dim3(256), 0, stream>>>(x, Wih, bih, Whh, bhh, y, hq);
}

// Round 8
// 4997.622 us; speedup vs baseline: 1.5691x; 1.5691x over previous
//
#include <hip/hip_runtime.h>
#include <stdint.h>

// LSTM N=32, T=2048, D=H=512. Persistent kernel, 8 groups x 32 WGs (grid=256=#CUs,
// co-resident). Each WG owns 16 hidden units (64 gate rows); weights stationary in
// VGPR MFMA A-fragments, rows ordered unit*4+gate. x and h split hi/lo bf16
// (two MFMA chains) for ~f32 accuracy.
//
// R11 = R8 skeleton (best verified sync structure, 5632us) + two isolated wins:
// 1) hi/lo PLANE LDS layout (R10-verified addressing): fragment loads are plain
//    ds_read_b128; perms drop from 256/lane/step (buildfrag) to 8/lane/step
//    (h-strip). R10 measured this as -37% VALU cycles.
// 2) direct f32 x staging with EARLY register load: x(t+1) issued at step top
//    (before h-load issue -> poll's vmcnt(0) covers it under the x-MFMA window);
//    LDS plane write happens after the mid barrier as pure VALU work. Deletes
//    the 128MiB xpk prologue + group barrier + ~256MB MALL traffic and the
//    end-of-step HBM stall.
// CRITICAL (R10 post-mortem): publish st_mall2 + y store stay BEFORE the end
// barrier -- the barrier's vmcnt(0) drain guarantees h(t) is globally visible
// before any WG enters step t+1, so consumer speculative loads hit fresh tags
// first try. Moving publish after the barrier cost R10 ~1us/step in retries.
// h exchange: R8's tagged fire-and-forget protocol verbatim, all sc0 sc1 (MALL;
// R5/R6 proved sc0-only cross-WG unreliable).

#define T_STEPS 2048
#define HD 512
#define NBATCH 32
#define PSTRIDE 260   // plane row stride (dwords): 260%32==4 -> 2-way max (free)

typedef __attribute__((ext_vector_type(8))) short short8;
typedef __attribute__((ext_vector_type(4))) float f32x4;
typedef __attribute__((ext_vector_type(4))) uint u32x4;
typedef __attribute__((ext_vector_type(2))) uint u32x2;

static __device__ __forceinline__ uint bf_rne(float f) {
    uint u = __builtin_bit_cast(uint, f);
    return (u + 0x7FFFu + ((u >> 16) & 1u)) >> 16;
}
static __device__ __forceinline__ float bf_f(uint h) {
    return __builtin_bit_cast(float, h << 16);
}
// f32 -> (bf16_hi<<16) | bf16_lo  (publish format)
static __device__ __forceinline__ uint packsplit(float f) {
    uint hi = bf_rne(f);
    uint lo = bf_rne(f - bf_f(hi));
    return (hi << 16) | lo;
}

static __device__ __forceinline__ float sigf(float v) { return 1.f / (1.f + __expf(-v)); }
static __device__ __forceinline__ float tanhfast(float v) { return 2.f / (1.f + __expf(-2.f * v)) - 1.f; }

// ---- MALL-coherent (device-scope) ops: sc0 sc1 bypass L1/L2 ----
static __device__ __forceinline__ void st_mall2(uint* p, u32x2 v) {
    asm volatile("global_store_dwordx2 %0, %1, off sc0 sc1" :: "v"(p), "v"(v) : "memory");
}
// issue four 16B tagged loads (no wait) — results unread until a tied wait
static __device__ __forceinline__ void ld_mall_issue4(const uint* p0, const uint* p1,
                                                      const uint* p2, const uint* p3,
                                                      u32x4& a, u32x4& b, u32x4& c, u32x4& d) {
    asm volatile("global_load_dwordx4 %0, %4, off sc0 sc1\n\t"
                 "global_load_dwordx4 %1, %5, off sc0 sc1\n\t"
                 "global_load_dwordx4 %2, %6, off sc0 sc1\n\t"
                 "global_load_dwordx4 %3, %7, off sc0 sc1"
                 : "=&v"(a), "=&v"(b), "=&v"(c), "=&v"(d)
                 : "v"(p0), "v"(p1), "v"(p2), "v"(p3) : "memory");
}
static __device__ __forceinline__ void wait_tied4(u32x4& a, u32x4& b, u32x4& c, u32x4& d) {
    asm volatile("s_waitcnt vmcnt(0)" : "+v"(a), "+v"(b), "+v"(c), "+v"(d) :: "memory");
}

__global__ __launch_bounds__(256, 1) void lstm_pers(
    const float* __restrict__ x, const float* __restrict__ Wih,
    const float* __restrict__ bih, const float* __restrict__ Whh,
    const float* __restrict__ bhh, float* __restrict__ y,
    uint* __restrict__ hq)
{
    // hi/lo bf16 planes: row = one batch, 256 dwords = 512 bf16 (k-major, 2/word)
    __shared__ uint xsh_hi[4 * PSTRIDE], xsh_lo[4 * PSTRIDE];
    __shared__ uint hs_hi[4 * PSTRIDE], hs_lo[4 * PSTRIDE];

    const int b   = blockIdx.x;
    const int g   = b & 7;
    const int w   = b >> 3;
    const int tid = threadIdx.x;
    const int wv  = tid >> 6;
    const int l   = tid & 63;
    const int q   = l >> 4;
    const int m   = l & 15;

    // ---- stationary weight A-fragments: rows ordered unit*4+gate ----
    const int gateA = m & 3, ulA = m >> 2;
    const int Arow  = gateA * HD + ((w << 4) + (wv << 2) + ulA);
    short8 wf[32];
#pragma unroll
    for (int kt = 0; kt < 32; ++kt) {
        const int k0 = kt * 32 + q * 8;
        const float* src = (k0 < HD) ? (Wih + (size_t)Arow * HD + k0)
                                     : (Whh + (size_t)Arow * HD + (k0 - HD));
        float4 a  = ((const float4*)src)[0];
        float4 c4 = ((const float4*)src)[1];
        uint4 uu;
        uu.x = bf_rne(a.x)  | (bf_rne(a.y)  << 16);
        uu.y = bf_rne(a.z)  | (bf_rne(a.w)  << 16);
        uu.z = bf_rne(c4.x) | (bf_rne(c4.y) << 16);
        uu.w = bf_rne(c4.z) | (bf_rne(c4.w) << 16);
        wf[kt] = __builtin_bit_cast(short8, uu);
    }

    const int unitC = (w << 4) + (wv << 2) + q;
    float bias_[4];
#pragma unroll
    for (int i = 0; i < 4; ++i) bias_[i] = bih[i * HD + unitC] + bhh[i * HD + unitC];

    const bool act = (m < 4);
    const int  fro = (l & 3) * PSTRIDE;     // fragment-read row base
    int budget = 1 << 21;                   // spin budget: guarantees termination

    // pack one float4 (4 consecutive k) into hi/lo plane words at widx (2 words)
    auto pack_x = [&](const float4& f, int widx) {
        uint h0 = bf_rne(f.x), h1 = bf_rne(f.y), h2 = bf_rne(f.z), h3 = bf_rne(f.w);
        uint l0 = bf_rne(f.x - bf_f(h0)), l1 = bf_rne(f.y - bf_f(h1));
        uint l2 = bf_rne(f.z - bf_f(h2)), l3 = bf_rne(f.w - bf_f(h3));
        u32x2 hw; hw.x = h0 | (h1 << 16); hw.y = h2 | (h3 << 16);
        u32x2 lw; lw.x = l0 | (l1 << 16); lw.y = l2 | (l3 << 16);
        *(u32x2*)&xsh_hi[wv * PSTRIDE + widx] = hw;
        *(u32x2*)&xsh_lo[wv * PSTRIDE + widx] = lw;
    };

    // ---- prologue: stage x(0) into planes (no xpk, no group barrier needed:
    //      first h exchange self-synchronizes via zeroed tags) ----
    {
        const float* xp = x + (size_t)(g * 4 + wv) * T_STEPS * HD;
        float4 A = *(const float4*)(xp + 4 * l);
        float4 C = *(const float4*)(xp + 256 + 4 * l);
        pack_x(A, 2 * l);
        pack_x(C, 128 + 2 * l);
    }
    __syncthreads();

    const f32x4 zero4 = {0.f, 0.f, 0.f, 0.f};
    float cst = 0.f;

    for (int t = 0; t < T_STEPS; ++t) {
        f32x4 a0 = zero4, a1 = zero4, b0 = zero4, b1 = zero4;
        u32x4 va, vb, vc, vd;
        float4 XA, XC;
        const bool havex = (t + 1 < T_STEPS);

        // --- issue phase: x(t+1) loads first (oldest), then h loads ---
        if (havex) {
            const float* xp = x + ((size_t)(g * 4 + wv) * T_STEPS + t + 1) * HD;
            XA = *(const float4*)(xp + 4 * l);
            XC = *(const float4*)(xp + 256 + 4 * l);
        }
        uint* const hp = hq + (size_t)(((t - 1) & 1) * NBATCH + g * 4 + wv) * (HD * 2);
        if (t > 0)
            ld_mall_issue4(hp + 4 * l, hp + 256 + 4 * l, hp + 512 + 4 * l,
                           hp + 768 + 4 * l, va, vb, vc, vd);

        // --- x-projection MFMA from planes (staged last step) ---
#pragma unroll
        for (int kt = 0; kt < 16; ++kt) {
            short8 bh = *(const short8*)&xsh_hi[fro + kt * 16 + q * 4];
            short8 bl = *(const short8*)&xsh_lo[fro + kt * 16 + q * 4];
            if (kt & 1) {
                a1 = __builtin_amdgcn_mfma_f32_16x16x32_bf16(wf[kt], bh, a1, 0, 0, 0);
                b1 = __builtin_amdgcn_mfma_f32_16x16x32_bf16(wf[kt], bl, b1, 0, 0, 0);
            } else {
                a0 = __builtin_amdgcn_mfma_f32_16x16x32_bf16(wf[kt], bh, a0, 0, 0, 0);
                b0 = __builtin_amdgcn_mfma_f32_16x16x32_bf16(wf[kt], bl, b0, 0, 0, 0);
            }
        }

        if (t > 0) {
            // --- tag poll: drain all (x regs arrived during x-MFMA too) ---
            wait_tied4(va, vb, vc, vd);
            const uint want = (uint)t;
            for (;;) {
                int ok = (va.y == want) & (va.w == want) & (vb.y == want) & (vb.w == want)
                       & (vc.y == want) & (vc.w == want) & (vd.y == want) & (vd.w == want);
                if (__all(ok)) break;
                if (--budget <= 0) break;
                ld_mall_issue4(hp + 4 * l, hp + 256 + 4 * l, hp + 512 + 4 * l,
                               hp + 768 + 4 * l, va, vb, vc, vd);
                wait_tied4(va, vb, vc, vd);
            }
            // --- strip to planes: 2 perms per 16B, 8 ds_write_b32 total ---
            hs_hi[wv * PSTRIDE + l]       = __builtin_amdgcn_perm(va.z, va.x, 0x07060302u);
            hs_lo[wv * PSTRIDE + l]       = __builtin_amdgcn_perm(va.z, va.x, 0x05040100u);
            hs_hi[wv * PSTRIDE + 64 + l]  = __builtin_amdgcn_perm(vb.z, vb.x, 0x07060302u);
            hs_lo[wv * PSTRIDE + 64 + l]  = __builtin_amdgcn_perm(vb.z, vb.x, 0x05040100u);
            hs_hi[wv * PSTRIDE + 128 + l] = __builtin_amdgcn_perm(vc.z, vc.x, 0x07060302u);
            hs_lo[wv * PSTRIDE + 128 + l] = __builtin_amdgcn_perm(vc.z, vc.x, 0x05040100u);
            hs_hi[wv * PSTRIDE + 192 + l] = __builtin_amdgcn_perm(vd.z, vd.x, 0x07060302u);
            hs_lo[wv * PSTRIDE + 192 + l] = __builtin_amdgcn_perm(vd.z, vd.x, 0x05040100u);
        }
        __syncthreads();   // hs ready; this step's xsh reads done (stage below)

        // --- stage x(t+1) into planes (regs already resident; pure VALU+LDS) ---
        if (havex) {
            pack_x(XA, 2 * l);
            pack_x(XC, 128 + 2 * l);
        }

        // --- h-recurrence MFMA ---
        if (t > 0) {
#pragma unroll
            for (int kt = 0; kt < 16; ++kt) {
                short8 bh = *(const short8*)&hs_hi[fro + kt * 16 + q * 4];
                short8 bl = *(const short8*)&hs_lo[fro + kt * 16 + q * 4];
                if (kt & 1) {
                    a1 = __builtin_amdgcn_mfma_f32_16x16x32_bf16(wf[16 + kt], bh, a1, 0, 0, 0);
                    b1 = __builtin_amdgcn_mfma_f32_16x16x32_bf16(wf[16 + kt], bl, b1, 0, 0, 0);
                } else {
                    a0 = __builtin_amdgcn_mfma_f32_16x16x32_bf16(wf[16 + kt], bh, a0, 0, 0, 0);
                    b0 = __builtin_amdgcn_mfma_f32_16x16x32_bf16(wf[16 + kt], bl, b0, 0, 0, 0);
                }
            }
        }

        // --- activation (act lanes own one unit each) ---
        const float v0 = a0.x + a1.x + b0.x + b1.x + bias_[0];   // i
        const float v1 = a0.y + a1.y + b0.y + b1.y + bias_[1];   // f
        const float v2 = a0.z + a1.z + b0.z + b1.z + bias_[2];   // o
        const float v3 = a0.w + a1.w + b0.w + b1.w + bias_[3];   // g
        const float ig = sigf(v0), fg = sigf(v1), og = sigf(v2), gg = tanhfast(v3);
        cst = fg * cst + ig * gg;
        const float hv = og * tanhfast(cst);

        if (act) {
            // publish BEFORE the end barrier (R10 lesson: the barrier's vmcnt(0)
            // drain makes h(t) globally visible before any WG enters step t+1)
            const uint p  = packsplit(hv);
            const int  bi = g * 4 + m;
            uint* dst = hq + (size_t)((t & 1) * NBATCH + bi) * (HD * 2) + unitC * 2;
            st_mall2(dst, (u32x2){p, (uint)t + 1u});
            y[((size_t)bi * T_STEPS + t) * HD + unitC] =
                __builtin_bit_cast(float, p & 0xFFFF0000u)
              + __builtin_bit_cast(float, p << 16);
        }

        __syncthreads();   // drains publish; hs reads done; xsh staged for t+1
    }
}

extern "C" void kernel_launch(void* const* d_in, const int* in_sizes, int n_in,
                              void* d_out, int out_size, void* d_ws, size_t ws_size,
                              hipStream_t stream) {
    (void)in_sizes; (void)n_in; (void)out_size; (void)ws_size;
    const float* x   = (const float*)d_in[0];
    const float* Wih = (const float*)d_in[1];
    const float* bih = (const float*)d_in[2];
    const float* Whh = (const float*)d_in[3];
    const float* bhh = (const float*)d_in[4];
    float* y = (float*)d_out;

    // workspace: tagged hbuf only (2 slots x 32 x 512 x 8B = 256K)
    uint* hq = (uint*)d_ws;
    // zero tags every launch (stale tags must never read as fresh)
    hipMemsetAsync(hq, 0, 262144, stream);
    lstm_pers<<<dim3(256), dim3(256), 0, stream>>>(x, Wih, bih, Whh, bhh, y, hq);
}

// Round 9
// 4997.022 us; speedup vs baseline: 1.5693x; 1.0001x over previous
//
#include <hip/hip_runtime.h>
#include <stdint.h>

// LSTM N=32, T=2048, D=H=512. Persistent kernel, 8 groups x 32 WGs (grid=256=#CUs,
// co-resident). Each WG owns 16 hidden units (64 gate rows); weights stationary in
// VGPR MFMA A-fragments, rows ordered unit*4+gate. x and h split hi/lo bf16
// (two MFMA chains) for ~f32 accuracy.
//
// R12 = R11 (4998us: plane LDS layout + async f32 x-stage + publish-before-
// barrier) + RAW BARRIERS: the in-loop __syncthreads() emitted s_waitcnt
// vmcnt(0) which serially drained the publish's MALL ack (~700cy) every step.
// The barrier only protects LDS reuse -> lgkmcnt(0)+s_barrier suffices. The
// publish ack now overlaps the next step's issue+x-MFMA window; consumers'
// tag poll (vmcnt(0)) naturally absorbs it. Protocol safety is unchanged:
// slot-overwrite ordering rests on data dependence (publish value depends on
// having read the previous slot), not on the drain. R10's lesson (publish
// ISSUE must precede the barrier) is preserved - only the DRAIN moved.
// h exchange: tagged fire-and-forget {payload, tag=t+1} dwordx2 sc0 sc1 (MALL);
// consumers speculatively load 4x dwordx4, poll tags == t. sc0-only XCD paths
// proven unreliable (R5/R6) - everything cross-WG stays MALL.

#define T_STEPS 2048
#define HD 512
#define NBATCH 32
#define PSTRIDE 260   // plane row stride (dwords): 260%32==4 -> 2-way max (free)

typedef __attribute__((ext_vector_type(8))) short short8;
typedef __attribute__((ext_vector_type(4))) float f32x4;
typedef __attribute__((ext_vector_type(4))) uint u32x4;
typedef __attribute__((ext_vector_type(2))) uint u32x2;

static __device__ __forceinline__ uint bf_rne(float f) {
    uint u = __builtin_bit_cast(uint, f);
    return (u + 0x7FFFu + ((u >> 16) & 1u)) >> 16;
}
static __device__ __forceinline__ float bf_f(uint h) {
    return __builtin_bit_cast(float, h << 16);
}
// f32 -> (bf16_hi<<16) | bf16_lo  (publish format)
static __device__ __forceinline__ uint packsplit(float f) {
    uint hi = bf_rne(f);
    uint lo = bf_rne(f - bf_f(hi));
    return (hi << 16) | lo;
}

static __device__ __forceinline__ float sigf(float v) { return 1.f / (1.f + __expf(-v)); }
static __device__ __forceinline__ float tanhfast(float v) { return 2.f / (1.f + __expf(-2.f * v)) - 1.f; }

// ---- MALL-coherent (device-scope) ops: sc0 sc1 bypass L1/L2 ----
static __device__ __forceinline__ void st_mall2(uint* p, u32x2 v) {
    asm volatile("global_store_dwordx2 %0, %1, off sc0 sc1" :: "v"(p), "v"(v) : "memory");
}
// issue four 16B tagged loads (no wait) — results unread until a tied wait
static __device__ __forceinline__ void ld_mall_issue4(const uint* p0, const uint* p1,
                                                      const uint* p2, const uint* p3,
                                                      u32x4& a, u32x4& b, u32x4& c, u32x4& d) {
    asm volatile("global_load_dwordx4 %0, %4, off sc0 sc1\n\t"
                 "global_load_dwordx4 %1, %5, off sc0 sc1\n\t"
                 "global_load_dwordx4 %2, %6, off sc0 sc1\n\t"
                 "global_load_dwordx4 %3, %7, off sc0 sc1"
                 : "=&v"(a), "=&v"(b), "=&v"(c), "=&v"(d)
                 : "v"(p0), "v"(p1), "v"(p2), "v"(p3) : "memory");
}
static __device__ __forceinline__ void wait_tied4(u32x4& a, u32x4& b, u32x4& c, u32x4& d) {
    asm volatile("s_waitcnt vmcnt(0)" : "+v"(a), "+v"(b), "+v"(c), "+v"(d) :: "memory");
}

// LDS-only barrier: orders ds ops across the WG WITHOUT draining vmcnt
// (the publish/y store acks overlap the next step's compute instead).
static __device__ __forceinline__ void barrier_lds() {
    __builtin_amdgcn_sched_barrier(0);
    asm volatile("s_waitcnt lgkmcnt(0)" ::: "memory");
    __builtin_amdgcn_s_barrier();
    __builtin_amdgcn_sched_barrier(0);
}

__global__ __launch_bounds__(256, 1) void lstm_pers(
    const float* __restrict__ x, const float* __restrict__ Wih,
    const float* __restrict__ bih, const float* __restrict__ Whh,
    const float* __restrict__ bhh, float* __restrict__ y,
    uint* __restrict__ hq)
{
    // hi/lo bf16 planes: row = one batch, 256 dwords = 512 bf16 (k-major, 2/word)
    __shared__ uint xsh_hi[4 * PSTRIDE], xsh_lo[4 * PSTRIDE];
    __shared__ uint hs_hi[4 * PSTRIDE], hs_lo[4 * PSTRIDE];

    const int b   = blockIdx.x;
    const int g   = b & 7;
    const int w   = b >> 3;
    const int tid = threadIdx.x;
    const int wv  = tid >> 6;
    const int l   = tid & 63;
    const int q   = l >> 4;
    const int m   = l & 15;

    // ---- stationary weight A-fragments: rows ordered unit*4+gate ----
    const int gateA = m & 3, ulA = m >> 2;
    const int Arow  = gateA * HD + ((w << 4) + (wv << 2) + ulA);
    short8 wf[32];
#pragma unroll
    for (int kt = 0; kt < 32; ++kt) {
        const int k0 = kt * 32 + q * 8;
        const float* src = (k0 < HD) ? (Wih + (size_t)Arow * HD + k0)
                                     : (Whh + (size_t)Arow * HD + (k0 - HD));
        float4 a  = ((const float4*)src)[0];
        float4 c4 = ((const float4*)src)[1];
        uint4 uu;
        uu.x = bf_rne(a.x)  | (bf_rne(a.y)  << 16);
        uu.y = bf_rne(a.z)  | (bf_rne(a.w)  << 16);
        uu.z = bf_rne(c4.x) | (bf_rne(c4.y) << 16);
        uu.w = bf_rne(c4.z) | (bf_rne(c4.w) << 16);
        wf[kt] = __builtin_bit_cast(short8, uu);
    }

    const int unitC = (w << 4) + (wv << 2) + q;
    float bias_[4];
#pragma unroll
    for (int i = 0; i < 4; ++i) bias_[i] = bih[i * HD + unitC] + bhh[i * HD + unitC];

    const bool act = (m < 4);
    const int  fro = (l & 3) * PSTRIDE;     // fragment-read row base
    int budget = 1 << 21;                   // spin budget: guarantees termination

    // pack one float4 (4 consecutive k) into hi/lo plane words at widx (2 words)
    auto pack_x = [&](const float4& f, int widx) {
        uint h0 = bf_rne(f.x), h1 = bf_rne(f.y), h2 = bf_rne(f.z), h3 = bf_rne(f.w);
        uint l0 = bf_rne(f.x - bf_f(h0)), l1 = bf_rne(f.y - bf_f(h1));
        uint l2 = bf_rne(f.z - bf_f(h2)), l3 = bf_rne(f.w - bf_f(h3));
        u32x2 hw; hw.x = h0 | (h1 << 16); hw.y = h2 | (h3 << 16);
        u32x2 lw; lw.x = l0 | (l1 << 16); lw.y = l2 | (l3 << 16);
        *(u32x2*)&xsh_hi[wv * PSTRIDE + widx] = hw;
        *(u32x2*)&xsh_lo[wv * PSTRIDE + widx] = lw;
    };

    // ---- prologue: stage x(0) into planes (no xpk, no group barrier needed:
    //      first h exchange self-synchronizes via zeroed tags) ----
    {
        const float* xp = x + (size_t)(g * 4 + wv) * T_STEPS * HD;
        float4 A = *(const float4*)(xp + 4 * l);
        float4 C = *(const float4*)(xp + 256 + 4 * l);
        pack_x(A, 2 * l);
        pack_x(C, 128 + 2 * l);
    }
    __syncthreads();

    const f32x4 zero4 = {0.f, 0.f, 0.f, 0.f};
    float cst = 0.f;

    for (int t = 0; t < T_STEPS; ++t) {
        f32x4 a0 = zero4, a1 = zero4, b0 = zero4, b1 = zero4;
        u32x4 va, vb, vc, vd;
        float4 XA, XC;
        const bool havex = (t + 1 < T_STEPS);

        // --- issue phase: x(t+1) loads first (oldest), then h loads ---
        if (havex) {
            const float* xp = x + ((size_t)(g * 4 + wv) * T_STEPS + t + 1) * HD;
            XA = *(const float4*)(xp + 4 * l);
            XC = *(const float4*)(xp + 256 + 4 * l);
        }
        uint* const hp = hq + (size_t)(((t - 1) & 1) * NBATCH + g * 4 + wv) * (HD * 2);
        if (t > 0)
            ld_mall_issue4(hp + 4 * l, hp + 256 + 4 * l, hp + 512 + 4 * l,
                           hp + 768 + 4 * l, va, vb, vc, vd);

        // --- x-projection MFMA from planes (staged last step) ---
#pragma unroll
        for (int kt = 0; kt < 16; ++kt) {
            short8 bh = *(const short8*)&xsh_hi[fro + kt * 16 + q * 4];
            short8 bl = *(const short8*)&xsh_lo[fro + kt * 16 + q * 4];
            if (kt & 1) {
                a1 = __builtin_amdgcn_mfma_f32_16x16x32_bf16(wf[kt], bh, a1, 0, 0, 0);
                b1 = __builtin_amdgcn_mfma_f32_16x16x32_bf16(wf[kt], bl, b1, 0, 0, 0);
            } else {
                a0 = __builtin_amdgcn_mfma_f32_16x16x32_bf16(wf[kt], bh, a0, 0, 0, 0);
                b0 = __builtin_amdgcn_mfma_f32_16x16x32_bf16(wf[kt], bl, b0, 0, 0, 0);
            }
        }

        if (t > 0) {
            // --- tag poll: drain all (x regs arrived during x-MFMA; also absorbs
            //     our previous step's publish ack, now un-drained by barriers) ---
            wait_tied4(va, vb, vc, vd);
            const uint want = (uint)t;
            for (;;) {
                int ok = (va.y == want) & (va.w == want) & (vb.y == want) & (vb.w == want)
                       & (vc.y == want) & (vc.w == want) & (vd.y == want) & (vd.w == want);
                if (__all(ok)) break;
                if (--budget <= 0) break;
                ld_mall_issue4(hp + 4 * l, hp + 256 + 4 * l, hp + 512 + 4 * l,
                               hp + 768 + 4 * l, va, vb, vc, vd);
                wait_tied4(va, vb, vc, vd);
            }
            // --- strip to planes: 2 perms per 16B, 8 ds_write_b32 total ---
            hs_hi[wv * PSTRIDE + l]       = __builtin_amdgcn_perm(va.z, va.x, 0x07060302u);
            hs_lo[wv * PSTRIDE + l]       = __builtin_amdgcn_perm(va.z, va.x, 0x05040100u);
            hs_hi[wv * PSTRIDE + 64 + l]  = __builtin_amdgcn_perm(vb.z, vb.x, 0x07060302u);
            hs_lo[wv * PSTRIDE + 64 + l]  = __builtin_amdgcn_perm(vb.z, vb.x, 0x05040100u);
            hs_hi[wv * PSTRIDE + 128 + l] = __builtin_amdgcn_perm(vc.z, vc.x, 0x07060302u);
            hs_lo[wv * PSTRIDE + 128 + l] = __builtin_amdgcn_perm(vc.z, vc.x, 0x05040100u);
            hs_hi[wv * PSTRIDE + 192 + l] = __builtin_amdgcn_perm(vd.z, vd.x, 0x07060302u);
            hs_lo[wv * PSTRIDE + 192 + l] = __builtin_amdgcn_perm(vd.z, vd.x, 0x05040100u);
        }
        barrier_lds();     // hs ready; this step's xsh reads done (stage below)

        // --- stage x(t+1) into planes (regs already resident; pure VALU+LDS) ---
        if (havex) {
            pack_x(XA, 2 * l);
            pack_x(XC, 128 + 2 * l);
        }

        // --- h-recurrence MFMA ---
        if (t > 0) {
#pragma unroll
            for (int kt = 0; kt < 16; ++kt) {
                short8 bh = *(const short8*)&hs_hi[fro + kt * 16 + q * 4];
                short8 bl = *(const short8*)&hs_lo[fro + kt * 16 + q * 4];
                if (kt & 1) {
                    a1 = __builtin_amdgcn_mfma_f32_16x16x32_bf16(wf[16 + kt], bh, a1, 0, 0, 0);
                    b1 = __builtin_amdgcn_mfma_f32_16x16x32_bf16(wf[16 + kt], bl, b1, 0, 0, 0);
                } else {
                    a0 = __builtin_amdgcn_mfma_f32_16x16x32_bf16(wf[16 + kt], bh, a0, 0, 0, 0);
                    b0 = __builtin_amdgcn_mfma_f32_16x16x32_bf16(wf[16 + kt], bl, b0, 0, 0, 0);
                }
            }
        }

        // --- activation (act lanes own one unit each) ---
        const float v0 = a0.x + a1.x + b0.x + b1.x + bias_[0];   // i
        const float v1 = a0.y + a1.y + b0.y + b1.y + bias_[1];   // f
        const float v2 = a0.z + a1.z + b0.z + b1.z + bias_[2];   // o
        const float v3 = a0.w + a1.w + b0.w + b1.w + bias_[3];   // g
        const float ig = sigf(v0), fg = sigf(v1), og = sigf(v2), gg = tanhfast(v3);
        cst = fg * cst + ig * gg;
        const float hv = og * tanhfast(cst);

        if (act) {
            // publish ISSUE before the end barrier (R10 lesson); its ACK is no
            // longer drained here (raw barrier) and overlaps the next step
            const uint p  = packsplit(hv);
            const int  bi = g * 4 + m;
            uint* dst = hq + (size_t)((t & 1) * NBATCH + bi) * (HD * 2) + unitC * 2;
            st_mall2(dst, (u32x2){p, (uint)t + 1u});
            y[((size_t)bi * T_STEPS + t) * HD + unitC] =
                __builtin_bit_cast(float, p & 0xFFFF0000u)
              + __builtin_bit_cast(float, p << 16);
        }

        barrier_lds();     // hs reads done; xsh staged for t+1 (no vmcnt drain)
    }
}

extern "C" void kernel_launch(void* const* d_in, const int* in_sizes, int n_in,
                              void* d_out, int out_size, void* d_ws, size_t ws_size,
                              hipStream_t stream) {
    (void)in_sizes; (void)n_in; (void)out_size; (void)ws_size;
    const float* x   = (const float*)d_in[0];
    const float* Wih = (const float*)d_in[1];
    const float* bih = (const float*)d_in[2];
    const float* Whh = (const float*)d_in[3];
    const float* bhh = (const float*)d_in[4];
    float* y = (float*)d_out;

    // workspace: tagged hbuf only (2 slots x 32 x 512 x 8B = 256K)
    uint* hq = (uint*)d_ws;
    // zero tags every launch (stale tags must never read as fresh)
    hipMemsetAsync(hq, 0, 262144, stream);
    lstm_pers<<<dim3(256), dim3(256), 0, stream>>>(x, Wih, bih, Whh, bhh, y, hq);
}